// Round 5
// baseline (108.692 us; speedup 1.0000x reference)
//
#include <hip/hip_runtime.h>
#include <hip/hip_bf16.h>

typedef __bf16 bf16_t;
typedef __bf16 bf16x8 __attribute__((ext_vector_type(8)));
typedef float f32x4 __attribute__((ext_vector_type(4)));
typedef float f32x16 __attribute__((ext_vector_type(16)));
typedef unsigned uint2v __attribute__((ext_vector_type(2)));

#define MFMA16(a, b, c) __builtin_amdgcn_mfma_f32_16x16x32_bf16((a), (b), (c), 0, 0, 0)
#define MFMA32(a, b, c) __builtin_amdgcn_mfma_f32_32x32x16_bf16((a), (b), (c), 0, 0, 0)

static constexpr int BB = 4, SS = 1024, HH = 1024, NHEAD = 16, HDIM = 64;
static constexpr int MM = BB * SS;  // 4096

__device__ __forceinline__ void gload_lds16(const void* g, void* l) {
  __builtin_amdgcn_global_load_lds((const __attribute__((address_space(1))) void*)g,
                                   (__attribute__((address_space(3))) void*)l, 16, 0, 0);
}

#if __has_builtin(__builtin_amdgcn_permlane32_swap)
#define PSWAP(a, b)                                                    \
  {                                                                    \
    uint2v _r = __builtin_amdgcn_permlane32_swap((a), (b), false, false); \
    (a) = _r.x;                                                        \
    (b) = _r.y;                                                        \
  }
#else
#define PSWAP(a, b) asm("v_permlane32_swap_b32 %0, %1" : "+v"(a), "+v"(b))
#endif

// ---------------- fp32 -> bf16 convert (hidden) ----------------
__global__ __launch_bounds__(256) void cvt_bf16_kernel(const float* __restrict__ in,
                                                       bf16_t* __restrict__ out, int n) {
  int i = (blockIdx.x * 256 + threadIdx.x) * 8;
  if (i >= n) return;
  float4 a = *(const float4*)(in + i);
  float4 b = *(const float4*)(in + i + 4);
  union { int4 i4; bf16_t h[8]; } u;
  u.h[0] = (bf16_t)a.x; u.h[1] = (bf16_t)a.y; u.h[2] = (bf16_t)a.z; u.h[3] = (bf16_t)a.w;
  u.h[4] = (bf16_t)b.x; u.h[5] = (bf16_t)b.y; u.h[6] = (bf16_t)b.z; u.h[7] = (bf16_t)b.w;
  *(int4*)(out + i) = u.i4;
}

// ---------------- W [k][n] fp32 -> WT [n][k] bf16 ----------------
__global__ __launch_bounds__(256) void transposeW_kernel(const float* __restrict__ Wq,
                                                         const float* __restrict__ Wk,
                                                         const float* __restrict__ Wv,
                                                         bf16_t* __restrict__ WT) {
  __shared__ float tile[32][33];
  int z = blockIdx.z;
  const float* W = (z == 0) ? Wq : (z == 1) ? Wk : Wv;
  bf16_t* Out = WT + (size_t)z * HH * HH;
  int tx = threadIdx.x, ty = threadIdx.y;
  int x0 = blockIdx.x * 32;  // n
  int y0 = blockIdx.y * 32;  // k
  for (int j = ty; j < 32; j += 8)
    tile[j][tx] = W[(size_t)(y0 + j) * HH + x0 + tx];
  __syncthreads();
  for (int j = ty; j < 32; j += 8)
    Out[(size_t)(x0 + j) * HH + y0 + tx] = (bf16_t)tile[tx][j];
}

// ---------------- QKV GEMM: BM=128 x BN=384, BK=64, 256 blocks (1/CU), 2-buf ----------------
#define BMT 128
#define BNT 384
#define BKT 64
#define NTL 16
#define BUFBYTES 65536  // (128+384)*64*2

__global__ __launch_bounds__(512, 2) void qkv_gemm2(const bf16_t* __restrict__ hiddenB,
                                                    const bf16_t* __restrict__ WT,
                                                    const float* __restrict__ bq,
                                                    const float* __restrict__ bk,
                                                    const float* __restrict__ bv,
                                                    bf16_t* __restrict__ Qo,
                                                    bf16_t* __restrict__ Ko,
                                                    bf16_t* __restrict__ Vt) {
  __shared__ bf16_t smem[2 * BUFBYTES / 2];  // 128 KB

  // XCD swizzle: 256 wgs = 8 XCD x 32; nb fastest -> A panel + B slice stay per-XCD
  const int wg = blockIdx.x;
  const int id = (wg & 7) * 32 + (wg >> 3);
  const int nb = id & 7;    // N / 384
  const int mb = id >> 3;   // M / 128

  const int t = threadIdx.x;
  const int lane = t & 63;
  const int w = t >> 6;      // 0..7
  const int wr = w >> 2;     // 0..1 (M, 64 rows)
  const int wc = w & 3;      // 0..3 (N, 96 cols)
  const int lr = lane & 15;
  const int g4 = lane >> 4;  // 0..3

  const unsigned schunk = (((unsigned)(t & 7)) ^ ((unsigned)((t >> 3) & 7))) << 4;
  const char* Ag = (const char*)hiddenB + (size_t)(mb * BMT) * 2048;
  const char* Bg = (const char*)WT + (size_t)(nb * BNT) * 2048;

  // one issue = 64 rows x 128B = 8KB; thread t covers row (t>>3), chunk (t&7)
  auto stage = [&](const char* gb, int growbase, int kbyte, char* ldsdest) {
    gload_lds16(gb + (size_t)(growbase + (t >> 3)) * 2048 + kbyte + schunk,
                ldsdest + w * 1024);
  };
  const unsigned axor = ((unsigned)(lr & 7)) << 4;

  f32x4 acc[4][6] = {};

  // prologue: stage tile 0
  {
    char* S0 = (char*)smem;
    stage(Ag, 0, 0, S0);
    stage(Ag, 64, 0, S0 + 8192);
#pragma unroll
    for (int i = 0; i < 6; ++i) stage(Bg, i * 64, 0, S0 + 16384 + i * 8192);
  }
  asm volatile("s_waitcnt vmcnt(0)" ::: "memory");
  __builtin_amdgcn_s_barrier();

  for (int j = 0; j < NTL; ++j) {
    const char* Ab = (const char*)smem + (j & 1) * BUFBYTES;
    const char* Bb = Ab + 16384;
    char* Sb = (char*)smem + ((j + 1) & 1) * BUFBYTES;
    const int kb = (j + 1) * 128;
    const bool st = (j + 1 < NTL);

    if (st) { stage(Ag, 0, kb, Sb); stage(Ag, 64, kb, Sb + 8192); }

    bf16x8 af[4][2];
#pragma unroll
    for (int mi = 0; mi < 4; ++mi)
#pragma unroll
      for (int ks = 0; ks < 2; ++ks)
        af[mi][ks] = *(const bf16x8*)(Ab + (size_t)(wr * 64 + mi * 16 + lr) * 128 +
                                      (((unsigned)(ks * 64 + g4 * 16)) ^ axor));

#pragma unroll
    for (int p = 0; p < 3; ++p) {
      if (st) {
        stage(Bg, (2 * p) * 64, kb, Sb + 16384 + (2 * p) * 8192);
        stage(Bg, (2 * p + 1) * 64, kb, Sb + 16384 + (2 * p + 1) * 8192);
      }
      bf16x8 b0[2], b1[2];
#pragma unroll
      for (int ks = 0; ks < 2; ++ks) {
        b0[ks] = *(const bf16x8*)(Bb + (size_t)(wc * 96 + (2 * p) * 16 + lr) * 128 +
                                  (((unsigned)(ks * 64 + g4 * 16)) ^ axor));
        b1[ks] = *(const bf16x8*)(Bb + (size_t)(wc * 96 + (2 * p + 1) * 16 + lr) * 128 +
                                  (((unsigned)(ks * 64 + g4 * 16)) ^ axor));
      }
      __builtin_amdgcn_s_setprio(1);
#pragma unroll
      for (int mi = 0; mi < 4; ++mi)
#pragma unroll
        for (int ks = 0; ks < 2; ++ks) {
          acc[mi][2 * p] = MFMA16(af[mi][ks], b0[ks], acc[mi][2 * p]);
          acc[mi][2 * p + 1] = MFMA16(af[mi][ks], b1[ks], acc[mi][2 * p + 1]);
        }
      __builtin_amdgcn_s_setprio(0);
    }

    if (st) {
      asm volatile("s_waitcnt vmcnt(0)" ::: "memory");
      __builtin_amdgcn_s_barrier();
    }
  }

  // epilogue: bias + scatter; per 16-col chunk select z (chunks never straddle z)
#pragma unroll
  for (int ni = 0; ni < 6; ++ni) {
    int col = nb * BNT + wc * 96 + ni * 16 + lr;
    int z = col >> 10;
    int ci = col & 1023;
    const float* bias = (z == 0) ? bq : (z == 1) ? bk : bv;
    float bia = bias[ci];
    int hh = ci >> 6, d = ci & 63;
    if (z < 2) {
      bf16_t* Out = (z == 0) ? Qo : Ko;
#pragma unroll
      for (int mi = 0; mi < 4; ++mi) {
#pragma unroll
        for (int r = 0; r < 4; ++r) {
          int row = mb * BMT + wr * 64 + mi * 16 + g4 * 4 + r;
          int b = row >> 10, s = row & 1023;
          Out[((size_t)(b * NHEAD + hh) * SS + s) * HDIM + d] = (bf16_t)(acc[mi][ni][r] + bia);
        }
      }
    } else {
#pragma unroll
      for (int mi = 0; mi < 4; ++mi) {
        int row0 = mb * BMT + wr * 64 + mi * 16 + g4 * 4;
        int b = row0 >> 10, s0 = row0 & 1023;
        float v0 = acc[mi][ni][0] + bia, v1 = acc[mi][ni][1] + bia;
        float v2 = acc[mi][ni][2] + bia, v3 = acc[mi][ni][3] + bia;
        unsigned u0, u1;
        asm("v_cvt_pk_bf16_f32 %0, %1, %2" : "=v"(u0) : "v"(v0), "v"(v1));
        asm("v_cvt_pk_bf16_f32 %0, %1, %2" : "=v"(u1) : "v"(v2), "v"(v3));
        uint2 pv; pv.x = u0; pv.y = u1;
        *(uint2*)&Vt[((size_t)(b * NHEAD + hh) * HDIM + d) * SS + s0] = pv;
      }
    }
  }
}

// ---------------- fused flash attention v3: register-streaming, no barriers ----------------
// K/V per head = 128KB each -> L1/L2-resident; fragments loaded straight from global.
// Swapped QK^T (mfma32(K,Q)); P^T packed in-register (cvt_pk + permlane32_swap);
// O^T = mfma32(V^T, P^T). Scale 0.125 folded into Q (exponent-exact in bf16).
__global__ __launch_bounds__(256) void attn3_kernel(const bf16_t* __restrict__ Q,
                                                    const bf16_t* __restrict__ K,
                                                    const bf16_t* __restrict__ Vt,
                                                    const float* __restrict__ mask,
                                                    float* __restrict__ out) {
  __shared__ float Msm[SS];

  // chunked XCD swizzle: 512 wgs, 64 per XCD; one bh entirely within one XCD
  const int wg = blockIdx.x;
  const int id = (wg & 7) * 64 + (wg >> 3);
  const int xblk = id & 7;
  const int bh = id >> 3;

  const int b = bh >> 4;
  const int h = bh & 15;
  const int t = threadIdx.x;
  const int lane = t & 63;
  const int w = t >> 6;
  const int l31 = lane & 31;
  const int hi = lane >> 5;
  const int q0 = xblk * 128 + w * 32;

  const bf16_t* Qh = Q + (size_t)bh * SS * HDIM;
  const bf16_t* Kh = K + (size_t)bh * SS * HDIM;
  const bf16_t* Vh = Vt + (size_t)bh * HDIM * SS;  // [d][s]

  *(float4*)&Msm[t * 4] = *(const float4*)&mask[(size_t)b * SS + t * 4];
  __syncthreads();

  // Q fragments, pre-scaled by 1/8 (exact: exponent shift only)
  bf16x8 qb[4];
#pragma unroll
  for (int c = 0; c < 4; ++c) {
    bf16x8 q = *(const bf16x8*)&Qh[(size_t)(q0 + l31) * HDIM + c * 16 + hi * 8];
#pragma unroll
    for (int e = 0; e < 8; ++e) q[e] = (bf16_t)((float)q[e] * 0.125f);
    qb[c] = q;
  }

  f32x16 acc0 = {}, acc1 = {};
  float m_run = -1e30f, l_run = 0.f;

  bf16x8 kf[4];
#pragma unroll
  for (int c = 0; c < 4; ++c)
    kf[c] = *(const bf16x8*)&Kh[(size_t)l31 * HDIM + c * 16 + hi * 8];

  for (int kvb = 0; kvb < SS; kvb += 32) {
    // ---- S^T = K . Q^T ----
    f32x16 st = {};
    __builtin_amdgcn_s_setprio(1);
#pragma unroll
    for (int c = 0; c < 4; ++c) st = MFMA32(kf[c], qb[c], st);
    __builtin_amdgcn_s_setprio(0);

    // prefetch next K tile fragments (wraps harmlessly on last iter)
    const int nx = (kvb + 32) & (SS - 1);
    bf16x8 kfn[4];
#pragma unroll
    for (int c = 0; c < 4; ++c)
      kfn[c] = *(const bf16x8*)&Kh[(size_t)(nx + l31) * HDIM + c * 16 + hi * 8];
    // V^T fragments for this tile
    bf16x8 vf[2][2];
#pragma unroll
    for (int dch = 0; dch < 2; ++dch)
#pragma unroll
      for (int kvc = 0; kvc < 2; ++kvc)
        vf[dch][kvc] = *(const bf16x8*)&Vh[(size_t)(dch * 32 + l31) * SS + kvb + kvc * 16 + hi * 8];

    // ---- + mask ----
#pragma unroll
    for (int k2 = 0; k2 < 8; ++k2) {
      int off = 8 * (k2 >> 1) + 4 * hi + 2 * (k2 & 1);
      float2 mk = *(const float2*)&Msm[kvb + off];
      st[2 * k2] += mk.x;
      st[2 * k2 + 1] += mk.y;
    }
    // ---- online softmax ----
    float mj = fmaxf(fmaxf(fmaxf(st[0], st[1]), fmaxf(st[2], st[3])),
                     fmaxf(fmaxf(st[4], st[5]), fmaxf(st[6], st[7])));
    float mj2 = fmaxf(fmaxf(fmaxf(st[8], st[9]), fmaxf(st[10], st[11])),
                      fmaxf(fmaxf(st[12], st[13]), fmaxf(st[14], st[15])));
    mj = fmaxf(mj, mj2);
    mj = fmaxf(mj, __shfl_xor(mj, 32));
    if (!__all(mj <= m_run + 8.f)) {
      float mnew = fmaxf(m_run, mj);
      float corr = __expf(m_run - mnew);
#pragma unroll
      for (int r = 0; r < 16; ++r) { acc0[r] *= corr; acc1[r] *= corr; }
      l_run *= corr;
      m_run = mnew;
    }
    float ls = 0.f;
#pragma unroll
    for (int r = 0; r < 16; ++r) {
      float p = __expf(st[r] - m_run);
      st[r] = p;
      ls += p;
    }
    ls += __shfl_xor(ls, 32);
    l_run += ls;
    // ---- pack P^T into B-frags ----
    unsigned wd[8];
#pragma unroll
    for (int k2 = 0; k2 < 8; ++k2) {
      float lo = st[2 * k2], hip = st[2 * k2 + 1];
      unsigned r;
      asm("v_cvt_pk_bf16_f32 %0, %1, %2" : "=v"(r) : "v"(lo), "v"(hip));
      wd[k2] = r;
    }
    unsigned a0 = wd[0], b0 = wd[2]; PSWAP(a0, b0);
    unsigned a1 = wd[1], b1 = wd[3]; PSWAP(a1, b1);
    unsigned a2 = wd[4], b2 = wd[6]; PSWAP(a2, b2);
    unsigned a3 = wd[5], b3 = wd[7]; PSWAP(a3, b3);
    union { unsigned u[4]; bf16x8 v; } pf0, pf1;
    pf0.u[0] = a0; pf0.u[1] = a1; pf0.u[2] = b0; pf0.u[3] = b1;
    pf1.u[0] = a2; pf1.u[1] = a3; pf1.u[2] = b2; pf1.u[3] = b3;
    // ---- O^T += V^T . P^T ----
    __builtin_amdgcn_s_setprio(1);
    acc0 = MFMA32(vf[0][0], pf0.v, acc0);
    acc1 = MFMA32(vf[1][0], pf0.v, acc1);
    acc0 = MFMA32(vf[0][1], pf1.v, acc0);
    acc1 = MFMA32(vf[1][1], pf1.v, acc1);
    __builtin_amdgcn_s_setprio(0);

#pragma unroll
    for (int c = 0; c < 4; ++c) kf[c] = kfn[c];
  }

  // ---- epilogue: normalize, write fp32 [b][s=q][h*64+d] ----
  float rinv = 1.0f / l_run;
  int q = q0 + l31;
  float* ob = out + ((size_t)(b * SS + q)) * HH + h * HDIM;
#pragma unroll
  for (int g = 0; g < 4; ++g) {
    float4 o0, o1;
    o0.x = acc0[g * 4 + 0] * rinv; o0.y = acc0[g * 4 + 1] * rinv;
    o0.z = acc0[g * 4 + 2] * rinv; o0.w = acc0[g * 4 + 3] * rinv;
    o1.x = acc1[g * 4 + 0] * rinv; o1.y = acc1[g * 4 + 1] * rinv;
    o1.z = acc1[g * 4 + 2] * rinv; o1.w = acc1[g * 4 + 3] * rinv;
    *(float4*)&ob[g * 8 + 4 * hi] = o0;
    *(float4*)&ob[32 + g * 8 + 4 * hi] = o1;
  }
}

// ---------------- launch ----------------
extern "C" void kernel_launch(void* const* d_in, const int* in_sizes, int n_in,
                              void* d_out, int out_size, void* d_ws, size_t ws_size,
                              hipStream_t stream) {
  const float* hs   = (const float*)d_in[0];
  const float* mask = (const float*)d_in[1];
  const float* Wq   = (const float*)d_in[2];
  const float* bq   = (const float*)d_in[3];
  const float* Wk   = (const float*)d_in[4];
  const float* bk   = (const float*)d_in[5];
  const float* Wv   = (const float*)d_in[6];
  const float* bv   = (const float*)d_in[7];
  float* out = (float*)d_out;

  char* ws = (char*)d_ws;
  bf16_t* hiddenB = (bf16_t*)ws;                                  // 8 MB
  bf16_t* WT      = (bf16_t*)(ws + (size_t)8 * 1024 * 1024);      // 6 MB
  bf16_t* Qb      = (bf16_t*)(ws + (size_t)14 * 1024 * 1024);     // 8 MB
  bf16_t* Kb      = (bf16_t*)(ws + (size_t)22 * 1024 * 1024);     // 8 MB
  bf16_t* Vt      = (bf16_t*)(ws + (size_t)30 * 1024 * 1024);     // 8 MB

  cvt_bf16_kernel<<<MM * HH / (256 * 8), 256, 0, stream>>>(hs, hiddenB, MM * HH);
  transposeW_kernel<<<dim3(32, 32, 3), dim3(32, 8), 0, stream>>>(Wq, Wk, Wv, WT);
  qkv_gemm2<<<256, 512, 0, stream>>>(hiddenB, WT, bq, bk, bv, Qb, Kb, Vt);
  attn3_kernel<<<512, 256, 0, stream>>>(Qb, Kb, Vt, mask, out);
}

// Round 6
// 82.096 us; speedup vs baseline: 1.3240x; 1.3240x over previous
//
#include <hip/hip_runtime.h>
#include <hip/hip_bf16.h>

typedef __bf16 bf16_t;
typedef __bf16 bf16x8 __attribute__((ext_vector_type(8)));
typedef float f32x4 __attribute__((ext_vector_type(4)));
typedef float f32x16 __attribute__((ext_vector_type(16)));
typedef unsigned uint2v __attribute__((ext_vector_type(2)));

#define MFMA16(a, b, c) __builtin_amdgcn_mfma_f32_16x16x32_bf16((a), (b), (c), 0, 0, 0)
#define MFMA32(a, b, c) __builtin_amdgcn_mfma_f32_32x32x16_bf16((a), (b), (c), 0, 0, 0)

static constexpr int BB = 4, SS = 1024, HH = 1024, NHEAD = 16, HDIM = 64;
static constexpr int MM = BB * SS;  // 4096

__device__ __forceinline__ void gload_lds16(const void* g, void* l) {
  __builtin_amdgcn_global_load_lds((const __attribute__((address_space(1))) void*)g,
                                   (__attribute__((address_space(3))) void*)l, 16, 0, 0);
}

#if __has_builtin(__builtin_amdgcn_permlane32_swap)
#define PSWAP(a, b)                                                    \
  {                                                                    \
    uint2v _r = __builtin_amdgcn_permlane32_swap((a), (b), false, false); \
    (a) = _r.x;                                                        \
    (b) = _r.y;                                                        \
  }
#else
#define PSWAP(a, b) asm("v_permlane32_swap_b32 %0, %1" : "+v"(a), "+v"(b))
#endif

// ---------------- fp32 -> bf16 convert (hidden) ----------------
__global__ __launch_bounds__(256) void cvt_bf16_kernel(const float* __restrict__ in,
                                                       bf16_t* __restrict__ out, int n) {
  int i = (blockIdx.x * 256 + threadIdx.x) * 8;
  if (i >= n) return;
  float4 a = *(const float4*)(in + i);
  float4 b = *(const float4*)(in + i + 4);
  union { int4 i4; bf16_t h[8]; } u;
  u.h[0] = (bf16_t)a.x; u.h[1] = (bf16_t)a.y; u.h[2] = (bf16_t)a.z; u.h[3] = (bf16_t)a.w;
  u.h[4] = (bf16_t)b.x; u.h[5] = (bf16_t)b.y; u.h[6] = (bf16_t)b.z; u.h[7] = (bf16_t)b.w;
  *(int4*)(out + i) = u.i4;
}

// ---------------- W [k][n] fp32 -> WT [n][k] bf16 ----------------
__global__ __launch_bounds__(256) void transposeW_kernel(const float* __restrict__ Wq,
                                                         const float* __restrict__ Wk,
                                                         const float* __restrict__ Wv,
                                                         bf16_t* __restrict__ WT) {
  __shared__ float tile[32][33];
  int z = blockIdx.z;
  const float* W = (z == 0) ? Wq : (z == 1) ? Wk : Wv;
  bf16_t* Out = WT + (size_t)z * HH * HH;
  int tx = threadIdx.x, ty = threadIdx.y;
  int x0 = blockIdx.x * 32;  // n
  int y0 = blockIdx.y * 32;  // k
  for (int j = ty; j < 32; j += 8)
    tile[j][tx] = W[(size_t)(y0 + j) * HH + x0 + tx];
  __syncthreads();
  for (int j = ty; j < 32; j += 8)
    Out[(size_t)(x0 + j) * HH + y0 + tx] = (bf16_t)tile[tx][j];
}

// ---------------- QKV GEMM: BM=128 x BN=384, BK=64, 256 blocks (1/CU), 2-buf ----------------
#define BMT 128
#define BNT 384
#define BKT 64
#define NTL 16
#define BUFBYTES 65536  // (128+384)*64*2

__global__ __launch_bounds__(512, 2) void qkv_gemm2(const bf16_t* __restrict__ hiddenB,
                                                    const bf16_t* __restrict__ WT,
                                                    const float* __restrict__ bq,
                                                    const float* __restrict__ bk,
                                                    const float* __restrict__ bv,
                                                    bf16_t* __restrict__ Qo,
                                                    bf16_t* __restrict__ Ko,
                                                    bf16_t* __restrict__ Vt) {
  __shared__ bf16_t smem[2 * BUFBYTES / 2];  // 128 KB

  // XCD swizzle: 256 wgs = 8 XCD x 32; nb fastest -> A panel + B slice stay per-XCD
  const int wg = blockIdx.x;
  const int id = (wg & 7) * 32 + (wg >> 3);
  const int nb = id & 7;    // N / 384
  const int mb = id >> 3;   // M / 128

  const int t = threadIdx.x;
  const int lane = t & 63;
  const int w = t >> 6;      // 0..7
  const int wr = w >> 2;     // 0..1 (M, 64 rows)
  const int wc = w & 3;      // 0..3 (N, 96 cols)
  const int lr = lane & 15;
  const int g4 = lane >> 4;  // 0..3

  const unsigned schunk = (((unsigned)(t & 7)) ^ ((unsigned)((t >> 3) & 7))) << 4;
  const char* Ag = (const char*)hiddenB + (size_t)(mb * BMT) * 2048;
  const char* Bg = (const char*)WT + (size_t)(nb * BNT) * 2048;

  // one issue = 64 rows x 128B = 8KB; thread t covers row (t>>3), chunk (t&7)
  auto stage = [&](const char* gb, int growbase, int kbyte, char* ldsdest) {
    gload_lds16(gb + (size_t)(growbase + (t >> 3)) * 2048 + kbyte + schunk,
                ldsdest + w * 1024);
  };
  const unsigned axor = ((unsigned)(lr & 7)) << 4;

  f32x4 acc[4][6] = {};

  // prologue: stage tile 0
  {
    char* S0 = (char*)smem;
    stage(Ag, 0, 0, S0);
    stage(Ag, 64, 0, S0 + 8192);
#pragma unroll
    for (int i = 0; i < 6; ++i) stage(Bg, i * 64, 0, S0 + 16384 + i * 8192);
  }
  asm volatile("s_waitcnt vmcnt(0)" ::: "memory");
  __builtin_amdgcn_s_barrier();

  for (int j = 0; j < NTL; ++j) {
    const char* Ab = (const char*)smem + (j & 1) * BUFBYTES;
    const char* Bb = Ab + 16384;
    char* Sb = (char*)smem + ((j + 1) & 1) * BUFBYTES;
    const int kb = (j + 1) * 128;
    const bool st = (j + 1 < NTL);

    if (st) { stage(Ag, 0, kb, Sb); stage(Ag, 64, kb, Sb + 8192); }

    bf16x8 af[4][2];
#pragma unroll
    for (int mi = 0; mi < 4; ++mi)
#pragma unroll
      for (int ks = 0; ks < 2; ++ks)
        af[mi][ks] = *(const bf16x8*)(Ab + (size_t)(wr * 64 + mi * 16 + lr) * 128 +
                                      (((unsigned)(ks * 64 + g4 * 16)) ^ axor));

#pragma unroll
    for (int p = 0; p < 3; ++p) {
      if (st) {
        stage(Bg, (2 * p) * 64, kb, Sb + 16384 + (2 * p) * 8192);
        stage(Bg, (2 * p + 1) * 64, kb, Sb + 16384 + (2 * p + 1) * 8192);
      }
      bf16x8 b0[2], b1[2];
#pragma unroll
      for (int ks = 0; ks < 2; ++ks) {
        b0[ks] = *(const bf16x8*)(Bb + (size_t)(wc * 96 + (2 * p) * 16 + lr) * 128 +
                                  (((unsigned)(ks * 64 + g4 * 16)) ^ axor));
        b1[ks] = *(const bf16x8*)(Bb + (size_t)(wc * 96 + (2 * p + 1) * 16 + lr) * 128 +
                                  (((unsigned)(ks * 64 + g4 * 16)) ^ axor));
      }
      __builtin_amdgcn_s_setprio(1);
#pragma unroll
      for (int mi = 0; mi < 4; ++mi)
#pragma unroll
        for (int ks = 0; ks < 2; ++ks) {
          acc[mi][2 * p] = MFMA16(af[mi][ks], b0[ks], acc[mi][2 * p]);
          acc[mi][2 * p + 1] = MFMA16(af[mi][ks], b1[ks], acc[mi][2 * p + 1]);
        }
      __builtin_amdgcn_s_setprio(0);
    }

    if (st) {
      asm volatile("s_waitcnt vmcnt(0)" ::: "memory");
      __builtin_amdgcn_s_barrier();
    }
  }

  // epilogue: bias + scatter; per 16-col chunk select z (chunks never straddle z)
#pragma unroll
  for (int ni = 0; ni < 6; ++ni) {
    int col = nb * BNT + wc * 96 + ni * 16 + lr;
    int z = col >> 10;
    int ci = col & 1023;
    const float* bias = (z == 0) ? bq : (z == 1) ? bk : bv;
    float bia = bias[ci];
    int hh = ci >> 6, d = ci & 63;
    if (z < 2) {
      bf16_t* Out = (z == 0) ? Qo : Ko;
#pragma unroll
      for (int mi = 0; mi < 4; ++mi) {
#pragma unroll
        for (int r = 0; r < 4; ++r) {
          int row = mb * BMT + wr * 64 + mi * 16 + g4 * 4 + r;
          int b = row >> 10, s = row & 1023;
          Out[((size_t)(b * NHEAD + hh) * SS + s) * HDIM + d] = (bf16_t)(acc[mi][ni][r] + bia);
        }
      }
    } else {
#pragma unroll
      for (int mi = 0; mi < 4; ++mi) {
        int row0 = mb * BMT + wr * 64 + mi * 16 + g4 * 4;
        int b = row0 >> 10, s0 = row0 & 1023;
        float v0 = acc[mi][ni][0] + bia, v1 = acc[mi][ni][1] + bia;
        float v2 = acc[mi][ni][2] + bia, v3 = acc[mi][ni][3] + bia;
        unsigned u0, u1;
        asm("v_cvt_pk_bf16_f32 %0, %1, %2" : "=v"(u0) : "v"(v0), "v"(v1));
        asm("v_cvt_pk_bf16_f32 %0, %1, %2" : "=v"(u1) : "v"(v2), "v"(v3));
        uint2 pv; pv.x = u0; pv.y = u1;
        *(uint2*)&Vt[((size_t)(b * NHEAD + hh) * HDIM + d) * SS + s0] = pv;
      }
    }
  }
}

// ---------------- fused flash attention v4: LDS-staged, 3-buffer counted-vmcnt ----------------
// Round-4 attn2 structure (swapped QK^T, 32x32 MFMA, in-register P packing) plus:
// 3-buffer K/V staging pipeline (stage tile t+2 while computing tile t), one
// barrier + counted vmcnt(4) per tile (drain-to-0 only at the tail). Q pre-scaled
// by 0.125 (exponent-exact in bf16).
__global__ __launch_bounds__(256) void attn4_kernel(const bf16_t* __restrict__ Q,
                                                    const bf16_t* __restrict__ K,
                                                    const bf16_t* __restrict__ Vt,
                                                    const float* __restrict__ mask,
                                                    float* __restrict__ out) {
  __shared__ bf16_t KVsm[3][2][64 * 64];  // [buf][K/V][8KB] = 48 KB
  __shared__ float Msm[SS];

  // chunked XCD swizzle: 512 wgs, 64 per XCD; one bh entirely within one XCD
  const int wg = blockIdx.x;
  const int id = (wg & 7) * 64 + (wg >> 3);
  const int xblk = id & 7;
  const int bh = id >> 3;

  const int b = bh >> 4;
  const int h = bh & 15;
  const int t = threadIdx.x;
  const int lane = t & 63;
  const int w = t >> 6;
  const int l31 = lane & 31;
  const int hi = lane >> 5;
  const int q0 = xblk * 128 + w * 32;

  const bf16_t* Qh = Q + (size_t)bh * SS * HDIM;
  const bf16_t* Kh = K + (size_t)bh * SS * HDIM;
  const bf16_t* Vh = Vt + (size_t)bh * HDIM * SS;  // [d][s]

  *(float4*)&Msm[t * 4] = *(const float4*)&mask[(size_t)b * SS + t * 4];

  // Q fragments pre-scaled by 1/8 (exact: exponent shift only)
  bf16x8 qb[4];
#pragma unroll
  for (int c = 0; c < 4; ++c) {
    bf16x8 q = *(const bf16x8*)&Qh[(size_t)(q0 + l31) * HDIM + c * 16 + hi * 8];
#pragma unroll
    for (int e = 0; e < 8; ++e) q[e] = (bf16_t)((float)q[e] * 0.125f);
    qb[c] = q;
  }

  const int srow = lane >> 3;
  const unsigned gcol = ((lane & 7) * 16) ^ (srow << 4);
  const unsigned swz = (unsigned)((l31 & 7) << 4);

  // stage K tile [kv0..kv0+64) rows and V^T cols [kv0..kv0+64): 4 gloads/thread
  auto stageKV = [&](int tile, int buf) {
    const int kv0 = tile * 64;
#pragma unroll
    for (int i = 0; i < 2; ++i) {
      int rbase = w * 16 + i * 8;
      gload_lds16((const char*)Kh + (size_t)(kv0 + rbase + srow) * 128 + gcol,
                  (char*)&KVsm[buf][0][0] + (size_t)rbase * 128);
      gload_lds16((const char*)Vh + (size_t)(rbase + srow) * 2048 + (size_t)kv0 * 2 + gcol,
                  (char*)&KVsm[buf][1][0] + (size_t)rbase * 128);
    }
  };

  f32x16 acc0 = {}, acc1 = {};
  float m_run = -1e30f, l_run = 0.f;

  stageKV(0, 0);
  stageKV(1, 1);
  asm volatile("s_waitcnt vmcnt(4) lgkmcnt(0)" ::: "memory");
  __builtin_amdgcn_s_barrier();

  for (int tt = 0; tt < 16; ++tt) {
    if (tt + 2 < 16) stageKV(tt + 2, (tt + 2) % 3);
    const char* Kb = (const char*)&KVsm[tt % 3][0][0];
    const char* Vb = (const char*)&KVsm[tt % 3][1][0];
    const int kv0 = tt * 64;

#pragma unroll
    for (int j = 0; j < 2; ++j) {
      // ---- S^T = K . (Q/8)^T ----
      f32x16 st = {};
      __builtin_amdgcn_s_setprio(1);
#pragma unroll
      for (int c = 0; c < 4; ++c) {
        bf16x8 kf = *(const bf16x8*)(Kb + (size_t)(j * 32 + l31) * 128 +
                                     ((unsigned)(c * 32 + hi * 16) ^ swz));
        st = MFMA32(kf, qb[c], st);
      }
      __builtin_amdgcn_s_setprio(0);
      // ---- + mask ----
#pragma unroll
      for (int k2 = 0; k2 < 8; ++k2) {
        int off = 8 * (k2 >> 1) + 4 * hi + 2 * (k2 & 1);
        float2 mk = *(const float2*)&Msm[kv0 + j * 32 + off];
        st[2 * k2] += mk.x;
        st[2 * k2 + 1] += mk.y;
      }
      // ---- online softmax (defer-max THR=8) ----
      float mj = st[0];
#pragma unroll
      for (int r = 1; r < 16; ++r) mj = fmaxf(mj, st[r]);
      mj = fmaxf(mj, __shfl_xor(mj, 32));
      if (!__all(mj <= m_run + 8.f)) {
        float mnew = fmaxf(m_run, mj);
        float corr = __expf(m_run - mnew);
#pragma unroll
        for (int r = 0; r < 16; ++r) { acc0[r] *= corr; acc1[r] *= corr; }
        l_run *= corr;
        m_run = mnew;
      }
      float ls = 0.f;
#pragma unroll
      for (int r = 0; r < 16; ++r) {
        float p = __expf(st[r] - m_run);
        st[r] = p;
        ls += p;
      }
      ls += __shfl_xor(ls, 32);
      l_run += ls;
      // ---- pack P^T into B-frags: cvt_pk + permlane32_swap ----
      unsigned wd[8];
#pragma unroll
      for (int k2 = 0; k2 < 8; ++k2) {
        float lo = st[2 * k2], hip = st[2 * k2 + 1];
        unsigned r;
        asm("v_cvt_pk_bf16_f32 %0, %1, %2" : "=v"(r) : "v"(lo), "v"(hip));
        wd[k2] = r;
      }
      unsigned a0 = wd[0], b0 = wd[2]; PSWAP(a0, b0);
      unsigned a1 = wd[1], b1 = wd[3]; PSWAP(a1, b1);
      unsigned a2 = wd[4], b2 = wd[6]; PSWAP(a2, b2);
      unsigned a3 = wd[5], b3 = wd[7]; PSWAP(a3, b3);
      union { unsigned u[4]; bf16x8 v; } pf0, pf1;
      pf0.u[0] = a0; pf0.u[1] = a1; pf0.u[2] = b0; pf0.u[3] = b1;
      pf1.u[0] = a2; pf1.u[1] = a3; pf1.u[2] = b2; pf1.u[3] = b3;
      // ---- O^T += V^T . P^T ----
      __builtin_amdgcn_s_setprio(1);
#pragma unroll
      for (int kvc = 0; kvc < 2; ++kvc) {
        bf16x8 pf = (kvc == 0) ? pf0.v : pf1.v;
#pragma unroll
        for (int dch = 0; dch < 2; ++dch) {
          bf16x8 vf = *(const bf16x8*)(Vb + (size_t)(dch * 32 + l31) * 128 +
                                       ((unsigned)(j * 64 + kvc * 32 + hi * 16) ^ swz));
          if (dch == 0) acc0 = MFMA32(vf, pf, acc0);
          else          acc1 = MFMA32(vf, pf, acc1);
        }
      }
      __builtin_amdgcn_s_setprio(0);
    }

    // trailing sync: wait for stage(tt+1) only (counted), keep stage(tt+2) in flight
    if (tt < 14) {
      asm volatile("s_waitcnt vmcnt(4)" ::: "memory");
      __builtin_amdgcn_s_barrier();
    } else if (tt == 14) {
      asm volatile("s_waitcnt vmcnt(0)" ::: "memory");
      __builtin_amdgcn_s_barrier();
    }
  }

  // ---- epilogue: normalize, write fp32 [b][s=q][h*64+d] ----
  float rinv = 1.0f / l_run;
  int q = q0 + l31;
  float* ob = out + ((size_t)(b * SS + q)) * HH + h * HDIM;
#pragma unroll
  for (int g = 0; g < 4; ++g) {
    float4 o0, o1;
    o0.x = acc0[g * 4 + 0] * rinv; o0.y = acc0[g * 4 + 1] * rinv;
    o0.z = acc0[g * 4 + 2] * rinv; o0.w = acc0[g * 4 + 3] * rinv;
    o1.x = acc1[g * 4 + 0] * rinv; o1.y = acc1[g * 4 + 1] * rinv;
    o1.z = acc1[g * 4 + 2] * rinv; o1.w = acc1[g * 4 + 3] * rinv;
    *(float4*)&ob[g * 8 + 4 * hi] = o0;
    *(float4*)&ob[32 + g * 8 + 4 * hi] = o1;
  }
}

// ---------------- launch ----------------
extern "C" void kernel_launch(void* const* d_in, const int* in_sizes, int n_in,
                              void* d_out, int out_size, void* d_ws, size_t ws_size,
                              hipStream_t stream) {
  const float* hs   = (const float*)d_in[0];
  const float* mask = (const float*)d_in[1];
  const float* Wq   = (const float*)d_in[2];
  const float* bq   = (const float*)d_in[3];
  const float* Wk   = (const float*)d_in[4];
  const float* bk   = (const float*)d_in[5];
  const float* Wv   = (const float*)d_in[6];
  const float* bv   = (const float*)d_in[7];
  float* out = (float*)d_out;

  char* ws = (char*)d_ws;
  bf16_t* hiddenB = (bf16_t*)ws;                                  // 8 MB
  bf16_t* WT      = (bf16_t*)(ws + (size_t)8 * 1024 * 1024);      // 6 MB
  bf16_t* Qb      = (bf16_t*)(ws + (size_t)14 * 1024 * 1024);     // 8 MB
  bf16_t* Kb      = (bf16_t*)(ws + (size_t)22 * 1024 * 1024);     // 8 MB
  bf16_t* Vt      = (bf16_t*)(ws + (size_t)30 * 1024 * 1024);     // 8 MB

  cvt_bf16_kernel<<<MM * HH / (256 * 8), 256, 0, stream>>>(hs, hiddenB, MM * HH);
  transposeW_kernel<<<dim3(32, 32, 3), dim3(32, 8), 0, stream>>>(Wq, Wk, Wv, WT);
  qkv_gemm2<<<256, 512, 0, stream>>>(hiddenB, WT, bq, bk, bv, Qb, Kb, Vt);
  attn4_kernel<<<512, 256, 0, stream>>>(Qb, Kb, Vt, mask, out);
}

// Round 7
// 78.698 us; speedup vs baseline: 1.3811x; 1.0432x over previous
//
#include <hip/hip_runtime.h>
#include <hip/hip_bf16.h>

typedef __bf16 bf16_t;
typedef __bf16 bf16x8 __attribute__((ext_vector_type(8)));
typedef float f32x4 __attribute__((ext_vector_type(4)));
typedef float f32x16 __attribute__((ext_vector_type(16)));
typedef unsigned uint2v __attribute__((ext_vector_type(2)));

#define MFMA16(a, b, c) __builtin_amdgcn_mfma_f32_16x16x32_bf16((a), (b), (c), 0, 0, 0)
#define MFMA32(a, b, c) __builtin_amdgcn_mfma_f32_32x32x16_bf16((a), (b), (c), 0, 0, 0)

static constexpr int BB = 4, SS = 1024, HH = 1024, NHEAD = 16, HDIM = 64;
static constexpr int MM = BB * SS;  // 4096

__device__ __forceinline__ void gload_lds16(const void* g, void* l) {
  __builtin_amdgcn_global_load_lds((const __attribute__((address_space(1))) void*)g,
                                   (__attribute__((address_space(3))) void*)l, 16, 0, 0);
}

#if __has_builtin(__builtin_amdgcn_permlane32_swap)
#define PSWAP(a, b)                                                    \
  {                                                                    \
    uint2v _r = __builtin_amdgcn_permlane32_swap((a), (b), false, false); \
    (a) = _r.x;                                                        \
    (b) = _r.y;                                                        \
  }
#else
#define PSWAP(a, b) asm("v_permlane32_swap_b32 %0, %1" : "+v"(a), "+v"(b))
#endif

#if __has_builtin(__builtin_amdgcn_exp2f)
__device__ __forceinline__ float EXP2(float x) { return __builtin_amdgcn_exp2f(x); }
#else
__device__ __forceinline__ float EXP2(float x) {
  float r;
  asm("v_exp_f32 %0, %1" : "=v"(r) : "v"(x));
  return r;
}
#endif

// ---------------- fp32 -> bf16 convert (hidden) ----------------
__global__ __launch_bounds__(256) void cvt_bf16_kernel(const float* __restrict__ in,
                                                       bf16_t* __restrict__ out, int n) {
  int i = (blockIdx.x * 256 + threadIdx.x) * 8;
  if (i >= n) return;
  float4 a = *(const float4*)(in + i);
  float4 b = *(const float4*)(in + i + 4);
  union { int4 i4; bf16_t h[8]; } u;
  u.h[0] = (bf16_t)a.x; u.h[1] = (bf16_t)a.y; u.h[2] = (bf16_t)a.z; u.h[3] = (bf16_t)a.w;
  u.h[4] = (bf16_t)b.x; u.h[5] = (bf16_t)b.y; u.h[6] = (bf16_t)b.z; u.h[7] = (bf16_t)b.w;
  *(int4*)(out + i) = u.i4;
}

// ---------------- W [k][n] fp32 -> WT [n][k] bf16 ----------------
__global__ __launch_bounds__(256) void transposeW_kernel(const float* __restrict__ Wq,
                                                         const float* __restrict__ Wk,
                                                         const float* __restrict__ Wv,
                                                         bf16_t* __restrict__ WT) {
  __shared__ float tile[32][33];
  int z = blockIdx.z;
  const float* W = (z == 0) ? Wq : (z == 1) ? Wk : Wv;
  bf16_t* Out = WT + (size_t)z * HH * HH;
  int tx = threadIdx.x, ty = threadIdx.y;
  int x0 = blockIdx.x * 32;  // n
  int y0 = blockIdx.y * 32;  // k
  for (int j = ty; j < 32; j += 8)
    tile[j][tx] = W[(size_t)(y0 + j) * HH + x0 + tx];
  __syncthreads();
  for (int j = ty; j < 32; j += 8)
    Out[(size_t)(x0 + j) * HH + y0 + tx] = (bf16_t)tile[tx][j];
}

// ---------------- QKV GEMM: BM=128 x BN=384, BK=64, 256 blocks (1/CU), 2-buf ----------------
#define BMT 128
#define BNT 384
#define BKT 64
#define NTL 16
#define BUFBYTES 65536  // (128+384)*64*2

__global__ __launch_bounds__(512, 2) void qkv_gemm2(const bf16_t* __restrict__ hiddenB,
                                                    const bf16_t* __restrict__ WT,
                                                    const float* __restrict__ bq,
                                                    const float* __restrict__ bk,
                                                    const float* __restrict__ bv,
                                                    bf16_t* __restrict__ Qo,
                                                    bf16_t* __restrict__ Ko,
                                                    bf16_t* __restrict__ Vt) {
  __shared__ bf16_t smem[2 * BUFBYTES / 2];  // 128 KB

  // XCD swizzle: 256 wgs = 8 XCD x 32; nb fastest -> A panel + B slice stay per-XCD
  const int wg = blockIdx.x;
  const int id = (wg & 7) * 32 + (wg >> 3);
  const int nb = id & 7;    // N / 384
  const int mb = id >> 3;   // M / 128

  const int t = threadIdx.x;
  const int lane = t & 63;
  const int w = t >> 6;      // 0..7
  const int wr = w >> 2;     // 0..1 (M, 64 rows)
  const int wc = w & 3;      // 0..3 (N, 96 cols)
  const int lr = lane & 15;
  const int g4 = lane >> 4;  // 0..3

  const unsigned schunk = (((unsigned)(t & 7)) ^ ((unsigned)((t >> 3) & 7))) << 4;
  const char* Ag = (const char*)hiddenB + (size_t)(mb * BMT) * 2048;
  const char* Bg = (const char*)WT + (size_t)(nb * BNT) * 2048;

  // one issue = 64 rows x 128B = 8KB; thread t covers row (t>>3), chunk (t&7)
  auto stage = [&](const char* gb, int growbase, int kbyte, char* ldsdest) {
    gload_lds16(gb + (size_t)(growbase + (t >> 3)) * 2048 + kbyte + schunk,
                ldsdest + w * 1024);
  };
  const unsigned axor = ((unsigned)(lr & 7)) << 4;

  f32x4 acc[4][6] = {};

  // prologue: stage tile 0
  {
    char* S0 = (char*)smem;
    stage(Ag, 0, 0, S0);
    stage(Ag, 64, 0, S0 + 8192);
#pragma unroll
    for (int i = 0; i < 6; ++i) stage(Bg, i * 64, 0, S0 + 16384 + i * 8192);
  }
  asm volatile("s_waitcnt vmcnt(0)" ::: "memory");
  __builtin_amdgcn_s_barrier();

  for (int j = 0; j < NTL; ++j) {
    const char* Ab = (const char*)smem + (j & 1) * BUFBYTES;
    const char* Bb = Ab + 16384;
    char* Sb = (char*)smem + ((j + 1) & 1) * BUFBYTES;
    const int kb = (j + 1) * 128;
    const bool st = (j + 1 < NTL);

    if (st) { stage(Ag, 0, kb, Sb); stage(Ag, 64, kb, Sb + 8192); }

    bf16x8 af[4][2];
#pragma unroll
    for (int mi = 0; mi < 4; ++mi)
#pragma unroll
      for (int ks = 0; ks < 2; ++ks)
        af[mi][ks] = *(const bf16x8*)(Ab + (size_t)(wr * 64 + mi * 16 + lr) * 128 +
                                      (((unsigned)(ks * 64 + g4 * 16)) ^ axor));

#pragma unroll
    for (int p = 0; p < 3; ++p) {
      if (st) {
        stage(Bg, (2 * p) * 64, kb, Sb + 16384 + (2 * p) * 8192);
        stage(Bg, (2 * p + 1) * 64, kb, Sb + 16384 + (2 * p + 1) * 8192);
      }
      bf16x8 b0[2], b1[2];
#pragma unroll
      for (int ks = 0; ks < 2; ++ks) {
        b0[ks] = *(const bf16x8*)(Bb + (size_t)(wc * 96 + (2 * p) * 16 + lr) * 128 +
                                  (((unsigned)(ks * 64 + g4 * 16)) ^ axor));
        b1[ks] = *(const bf16x8*)(Bb + (size_t)(wc * 96 + (2 * p + 1) * 16 + lr) * 128 +
                                  (((unsigned)(ks * 64 + g4 * 16)) ^ axor));
      }
      __builtin_amdgcn_s_setprio(1);
#pragma unroll
      for (int mi = 0; mi < 4; ++mi)
#pragma unroll
        for (int ks = 0; ks < 2; ++ks) {
          acc[mi][2 * p] = MFMA16(af[mi][ks], b0[ks], acc[mi][2 * p]);
          acc[mi][2 * p + 1] = MFMA16(af[mi][ks], b1[ks], acc[mi][2 * p + 1]);
        }
      __builtin_amdgcn_s_setprio(0);
    }

    if (st) {
      asm volatile("s_waitcnt vmcnt(0)" ::: "memory");
      __builtin_amdgcn_s_barrier();
    }
  }

  // epilogue: bias + scatter; per 16-col chunk select z (chunks never straddle z)
#pragma unroll
  for (int ni = 0; ni < 6; ++ni) {
    int col = nb * BNT + wc * 96 + ni * 16 + lr;
    int z = col >> 10;
    int ci = col & 1023;
    const float* bias = (z == 0) ? bq : (z == 1) ? bk : bv;
    float bia = bias[ci];
    int hh = ci >> 6, d = ci & 63;
    if (z < 2) {
      bf16_t* Out = (z == 0) ? Qo : Ko;
#pragma unroll
      for (int mi = 0; mi < 4; ++mi) {
#pragma unroll
        for (int r = 0; r < 4; ++r) {
          int row = mb * BMT + wr * 64 + mi * 16 + g4 * 4 + r;
          int b = row >> 10, s = row & 1023;
          Out[((size_t)(b * NHEAD + hh) * SS + s) * HDIM + d] = (bf16_t)(acc[mi][ni][r] + bia);
        }
      }
    } else {
#pragma unroll
      for (int mi = 0; mi < 4; ++mi) {
        int row0 = mb * BMT + wr * 64 + mi * 16 + g4 * 4;
        int b = row0 >> 10, s0 = row0 & 1023;
        float v0 = acc[mi][ni][0] + bia, v1 = acc[mi][ni][1] + bia;
        float v2 = acc[mi][ni][2] + bia, v3 = acc[mi][ni][3] + bia;
        unsigned u0, u1;
        asm("v_cvt_pk_bf16_f32 %0, %1, %2" : "=v"(u0) : "v"(v0), "v"(v1));
        asm("v_cvt_pk_bf16_f32 %0, %1, %2" : "=v"(u1) : "v"(v2), "v"(v3));
        uint2 pv; pv.x = u0; pv.y = u1;
        *(uint2*)&Vt[((size_t)(b * NHEAD + hh) * HDIM + d) * SS + s0] = pv;
      }
    }
  }
}

// ---------------- fused flash attention v5: batched-j softmax, log2 domain ----------------
// r6 structure (3-buffer counted-vmcnt staging, swapped QK^T 32x32, in-register P pack)
// with the per-tile dependency chain shortened:
//  - both j-subtiles' QK^T first, ONE softmax over 32 per-lane scores (2x ILP)
//  - v_max3 tree for max (depth ~5), balanced pairwise tree for sum (depth 5)
//  - log2-domain: Q pre-scaled by 0.125*log2e, mask staged *log2e, exp = v_exp_f32
__global__ __launch_bounds__(256) void attn5_kernel(const bf16_t* __restrict__ Q,
                                                    const bf16_t* __restrict__ K,
                                                    const bf16_t* __restrict__ Vt,
                                                    const float* __restrict__ mask,
                                                    float* __restrict__ out) {
  __shared__ bf16_t KVsm[3][2][64 * 64];  // 48 KB
  __shared__ float Msm[SS];

  const int wg = blockIdx.x;
  const int id = (wg & 7) * 64 + (wg >> 3);
  const int xblk = id & 7;
  const int bh = id >> 3;

  const int b = bh >> 4;
  const int h = bh & 15;
  const int t = threadIdx.x;
  const int lane = t & 63;
  const int w = t >> 6;
  const int l31 = lane & 31;
  const int hi = lane >> 5;
  const int q0 = xblk * 128 + w * 32;

  const bf16_t* Qh = Q + (size_t)bh * SS * HDIM;
  const bf16_t* Kh = K + (size_t)bh * SS * HDIM;
  const bf16_t* Vh = Vt + (size_t)bh * HDIM * SS;  // [d][s]

  const float L2E = 1.4426950408889634f;
  {
    float4 mv = *(const float4*)&mask[(size_t)b * SS + t * 4];
    mv.x *= L2E; mv.y *= L2E; mv.z *= L2E; mv.w *= L2E;
    *(float4*)&Msm[t * 4] = mv;
  }

  // Q fragments pre-scaled by 0.125*log2e (log2-domain scores)
  bf16x8 qb[4];
#pragma unroll
  for (int c = 0; c < 4; ++c) {
    bf16x8 q = *(const bf16x8*)&Qh[(size_t)(q0 + l31) * HDIM + c * 16 + hi * 8];
#pragma unroll
    for (int e = 0; e < 8; ++e) q[e] = (bf16_t)((float)q[e] * (0.125f * L2E));
    qb[c] = q;
  }

  const int srow = lane >> 3;
  const unsigned gcol = ((lane & 7) * 16) ^ (srow << 4);
  const unsigned swz = (unsigned)((l31 & 7) << 4);

  auto stageKV = [&](int tile, int buf) {
    const int kv0 = tile * 64;
#pragma unroll
    for (int i = 0; i < 2; ++i) {
      int rbase = w * 16 + i * 8;
      gload_lds16((const char*)Kh + (size_t)(kv0 + rbase + srow) * 128 + gcol,
                  (char*)&KVsm[buf][0][0] + (size_t)rbase * 128);
      gload_lds16((const char*)Vh + (size_t)(rbase + srow) * 2048 + (size_t)kv0 * 2 + gcol,
                  (char*)&KVsm[buf][1][0] + (size_t)rbase * 128);
    }
  };

  f32x16 acc0 = {}, acc1 = {};
  float m_run = -1e30f, l_run = 0.f;

  stageKV(0, 0);
  stageKV(1, 1);
  asm volatile("s_waitcnt vmcnt(4) lgkmcnt(0)" ::: "memory");
  __builtin_amdgcn_s_barrier();

  for (int tt = 0; tt < 16; ++tt) {
    if (tt + 2 < 16) stageKV(tt + 2, (tt + 2) % 3);
    const char* Kb = (const char*)&KVsm[tt % 3][0][0];
    const char* Vb = (const char*)&KVsm[tt % 3][1][0];
    const int kv0 = tt * 64;

    // ---- QK^T for both 32-kv halves ----
    f32x16 st0 = {}, st1 = {};
    __builtin_amdgcn_s_setprio(1);
#pragma unroll
    for (int c = 0; c < 4; ++c) {
      bf16x8 kf0 = *(const bf16x8*)(Kb + (size_t)l31 * 128 + ((unsigned)(c * 32 + hi * 16) ^ swz));
      st0 = MFMA32(kf0, qb[c], st0);
    }
#pragma unroll
    for (int c = 0; c < 4; ++c) {
      bf16x8 kf1 = *(const bf16x8*)(Kb + (size_t)(32 + l31) * 128 + ((unsigned)(c * 32 + hi * 16) ^ swz));
      st1 = MFMA32(kf1, qb[c], st1);
    }
    __builtin_amdgcn_s_setprio(0);

    // ---- + mask (log2-scaled) ----
#pragma unroll
    for (int k2 = 0; k2 < 8; ++k2) {
      int off = 8 * (k2 >> 1) + 4 * hi + 2 * (k2 & 1);
      float2 m0v = *(const float2*)&Msm[kv0 + off];
      float2 m1v = *(const float2*)&Msm[kv0 + 32 + off];
      st0[2 * k2] += m0v.x; st0[2 * k2 + 1] += m0v.y;
      st1[2 * k2] += m1v.x; st1[2 * k2 + 1] += m1v.y;
    }

    // ---- max via pairwise + v_max3 tree ----
    float v0 = fmaxf(st0[0], st1[0]),  v1 = fmaxf(st0[1], st1[1]);
    float v2 = fmaxf(st0[2], st1[2]),  v3 = fmaxf(st0[3], st1[3]);
    float v4 = fmaxf(st0[4], st1[4]),  v5 = fmaxf(st0[5], st1[5]);
    float v6 = fmaxf(st0[6], st1[6]),  v7 = fmaxf(st0[7], st1[7]);
    float v8 = fmaxf(st0[8], st1[8]),  v9 = fmaxf(st0[9], st1[9]);
    float v10 = fmaxf(st0[10], st1[10]), v11 = fmaxf(st0[11], st1[11]);
    float v12 = fmaxf(st0[12], st1[12]), v13 = fmaxf(st0[13], st1[13]);
    float v14 = fmaxf(st0[14], st1[14]), v15 = fmaxf(st0[15], st1[15]);
    float g0 = fmaxf(fmaxf(v0, v1), v2);
    float g1 = fmaxf(fmaxf(v3, v4), v5);
    float g2 = fmaxf(fmaxf(v6, v7), v8);
    float g3 = fmaxf(fmaxf(v9, v10), v11);
    float g4 = fmaxf(fmaxf(v12, v13), v14);
    float mj = fmaxf(fmaxf(fmaxf(g0, g1), g2), fmaxf(fmaxf(g3, g4), v15));
    mj = fmaxf(mj, __shfl_xor(mj, 32));

    // ---- defer-max (THR = 8 bits -> P <= 256) ----
    if (!__all(mj <= m_run + 8.f)) {
      float mnew = fmaxf(m_run, mj);
      float corr = EXP2(m_run - mnew);
#pragma unroll
      for (int r = 0; r < 16; ++r) { acc0[r] *= corr; acc1[r] *= corr; }
      l_run *= corr;
      m_run = mnew;
    }

    // ---- p = 2^(st - m) ----
#pragma unroll
    for (int r = 0; r < 16; ++r) st0[r] = EXP2(st0[r] - m_run);
#pragma unroll
    for (int r = 0; r < 16; ++r) st1[r] = EXP2(st1[r] - m_run);

    // ---- sum: balanced tree over 32 ----
    float s0 = (st0[0] + st1[0]) + (st0[1] + st1[1]);
    float s1 = (st0[2] + st1[2]) + (st0[3] + st1[3]);
    float s2 = (st0[4] + st1[4]) + (st0[5] + st1[5]);
    float s3 = (st0[6] + st1[6]) + (st0[7] + st1[7]);
    float s4 = (st0[8] + st1[8]) + (st0[9] + st1[9]);
    float s5 = (st0[10] + st1[10]) + (st0[11] + st1[11]);
    float s6 = (st0[12] + st1[12]) + (st0[13] + st1[13]);
    float s7 = (st0[14] + st1[14]) + (st0[15] + st1[15]);
    float ls = ((s0 + s1) + (s2 + s3)) + ((s4 + s5) + (s6 + s7));
    ls += __shfl_xor(ls, 32);
    l_run += ls;

    // ---- pack both P halves into B-frags ----
    unsigned wd0[8], wd1[8];
#pragma unroll
    for (int k2 = 0; k2 < 8; ++k2) {
      unsigned r0, r1;
      float a0f = st0[2 * k2], a1f = st0[2 * k2 + 1];
      float b0f = st1[2 * k2], b1f = st1[2 * k2 + 1];
      asm("v_cvt_pk_bf16_f32 %0, %1, %2" : "=v"(r0) : "v"(a0f), "v"(a1f));
      asm("v_cvt_pk_bf16_f32 %0, %1, %2" : "=v"(r1) : "v"(b0f), "v"(b1f));
      wd0[k2] = r0; wd1[k2] = r1;
    }
    unsigned a0 = wd0[0], b0 = wd0[2]; PSWAP(a0, b0);
    unsigned a1 = wd0[1], b1 = wd0[3]; PSWAP(a1, b1);
    unsigned a2 = wd0[4], b2 = wd0[6]; PSWAP(a2, b2);
    unsigned a3 = wd0[5], b3 = wd0[7]; PSWAP(a3, b3);
    unsigned c0 = wd1[0], d0 = wd1[2]; PSWAP(c0, d0);
    unsigned c1 = wd1[1], d1 = wd1[3]; PSWAP(c1, d1);
    unsigned c2 = wd1[4], d2 = wd1[6]; PSWAP(c2, d2);
    unsigned c3 = wd1[5], d3 = wd1[7]; PSWAP(c3, d3);
    union { unsigned u[4]; bf16x8 v; } pf0, pf1, pf2, pf3;
    pf0.u[0] = a0; pf0.u[1] = a1; pf0.u[2] = b0; pf0.u[3] = b1;
    pf1.u[0] = a2; pf1.u[1] = a3; pf1.u[2] = b2; pf1.u[3] = b3;
    pf2.u[0] = c0; pf2.u[1] = c1; pf2.u[2] = d0; pf2.u[3] = d1;
    pf3.u[0] = c2; pf3.u[1] = c3; pf3.u[2] = d2; pf3.u[3] = d3;

    // ---- O^T += V^T . P^T (both halves) ----
    __builtin_amdgcn_s_setprio(1);
    {
      bf16x8 vf;
      vf = *(const bf16x8*)(Vb + (size_t)(0 * 32 + l31) * 128 + ((unsigned)(0 * 64 + 0 * 32 + hi * 16) ^ swz));
      acc0 = MFMA32(vf, pf0.v, acc0);
      vf = *(const bf16x8*)(Vb + (size_t)(1 * 32 + l31) * 128 + ((unsigned)(0 * 64 + 0 * 32 + hi * 16) ^ swz));
      acc1 = MFMA32(vf, pf0.v, acc1);
      vf = *(const bf16x8*)(Vb + (size_t)(0 * 32 + l31) * 128 + ((unsigned)(0 * 64 + 1 * 32 + hi * 16) ^ swz));
      acc0 = MFMA32(vf, pf1.v, acc0);
      vf = *(const bf16x8*)(Vb + (size_t)(1 * 32 + l31) * 128 + ((unsigned)(0 * 64 + 1 * 32 + hi * 16) ^ swz));
      acc1 = MFMA32(vf, pf1.v, acc1);
      vf = *(const bf16x8*)(Vb + (size_t)(0 * 32 + l31) * 128 + ((unsigned)(1 * 64 + 0 * 32 + hi * 16) ^ swz));
      acc0 = MFMA32(vf, pf2.v, acc0);
      vf = *(const bf16x8*)(Vb + (size_t)(1 * 32 + l31) * 128 + ((unsigned)(1 * 64 + 0 * 32 + hi * 16) ^ swz));
      acc1 = MFMA32(vf, pf2.v, acc1);
      vf = *(const bf16x8*)(Vb + (size_t)(0 * 32 + l31) * 128 + ((unsigned)(1 * 64 + 1 * 32 + hi * 16) ^ swz));
      acc0 = MFMA32(vf, pf3.v, acc0);
      vf = *(const bf16x8*)(Vb + (size_t)(1 * 32 + l31) * 128 + ((unsigned)(1 * 64 + 1 * 32 + hi * 16) ^ swz));
      acc1 = MFMA32(vf, pf3.v, acc1);
    }
    __builtin_amdgcn_s_setprio(0);

    if (tt < 14) {
      asm volatile("s_waitcnt vmcnt(4)" ::: "memory");
      __builtin_amdgcn_s_barrier();
    } else if (tt == 14) {
      asm volatile("s_waitcnt vmcnt(0)" ::: "memory");
      __builtin_amdgcn_s_barrier();
    }
  }

  // ---- epilogue: normalize, write fp32 [b][s=q][h*64+d] ----
  float rinv = 1.0f / l_run;
  int q = q0 + l31;
  float* ob = out + ((size_t)(b * SS + q)) * HH + h * HDIM;
#pragma unroll
  for (int g = 0; g < 4; ++g) {
    float4 o0, o1;
    o0.x = acc0[g * 4 + 0] * rinv; o0.y = acc0[g * 4 + 1] * rinv;
    o0.z = acc0[g * 4 + 2] * rinv; o0.w = acc0[g * 4 + 3] * rinv;
    o1.x = acc1[g * 4 + 0] * rinv; o1.y = acc1[g * 4 + 1] * rinv;
    o1.z = acc1[g * 4 + 2] * rinv; o1.w = acc1[g * 4 + 3] * rinv;
    *(float4*)&ob[g * 8 + 4 * hi] = o0;
    *(float4*)&ob[32 + g * 8 + 4 * hi] = o1;
  }
}

// ---------------- launch ----------------
extern "C" void kernel_launch(void* const* d_in, const int* in_sizes, int n_in,
                              void* d_out, int out_size, void* d_ws, size_t ws_size,
                              hipStream_t stream) {
  const float* hs   = (const float*)d_in[0];
  const float* mask = (const float*)d_in[1];
  const float* Wq   = (const float*)d_in[2];
  const float* bq   = (const float*)d_in[3];
  const float* Wk   = (const float*)d_in[4];
  const float* bk   = (const float*)d_in[5];
  const float* Wv   = (const float*)d_in[6];
  const float* bv   = (const float*)d_in[7];
  float* out = (float*)d_out;

  char* ws = (char*)d_ws;
  bf16_t* hiddenB = (bf16_t*)ws;                                  // 8 MB
  bf16_t* WT      = (bf16_t*)(ws + (size_t)8 * 1024 * 1024);      // 6 MB
  bf16_t* Qb      = (bf16_t*)(ws + (size_t)14 * 1024 * 1024);     // 8 MB
  bf16_t* Kb      = (bf16_t*)(ws + (size_t)22 * 1024 * 1024);     // 8 MB
  bf16_t* Vt      = (bf16_t*)(ws + (size_t)30 * 1024 * 1024);     // 8 MB

  cvt_bf16_kernel<<<MM * HH / (256 * 8), 256, 0, stream>>>(hs, hiddenB, MM * HH);
  transposeW_kernel<<<dim3(32, 32, 3), dim3(32, 8), 0, stream>>>(Wq, Wk, Wv, WT);
  qkv_gemm2<<<256, 512, 0, stream>>>(hiddenB, WT, bq, bk, bv, Qb, Kb, Vt);
  attn5_kernel<<<512, 256, 0, stream>>>(Qb, Kb, Vt, mask, out);
}

// Round 9
// 74.997 us; speedup vs baseline: 1.4493x; 1.0493x over previous
//
#include <hip/hip_runtime.h>
#include <hip/hip_bf16.h>

typedef __bf16 bf16_t;
typedef __bf16 bf16x8 __attribute__((ext_vector_type(8)));
typedef float f32x4 __attribute__((ext_vector_type(4)));
typedef float f32x16 __attribute__((ext_vector_type(16)));
typedef unsigned uint2v __attribute__((ext_vector_type(2)));

#define MFMA16(a, b, c) __builtin_amdgcn_mfma_f32_16x16x32_bf16((a), (b), (c), 0, 0, 0)
#define MFMA32(a, b, c) __builtin_amdgcn_mfma_f32_32x32x16_bf16((a), (b), (c), 0, 0, 0)

static constexpr int BB = 4, SS = 1024, HH = 1024, NHEAD = 16, HDIM = 64;
static constexpr int MM = BB * SS;  // 4096

__device__ __forceinline__ void gload_lds16(const void* g, void* l) {
  __builtin_amdgcn_global_load_lds((const __attribute__((address_space(1))) void*)g,
                                   (__attribute__((address_space(3))) void*)l, 16, 0, 0);
}

#if __has_builtin(__builtin_amdgcn_permlane32_swap)
#define PSWAP(a, b)                                                    \
  {                                                                    \
    uint2v _r = __builtin_amdgcn_permlane32_swap((a), (b), false, false); \
    (a) = _r.x;                                                        \
    (b) = _r.y;                                                        \
  }
#else
#define PSWAP(a, b) asm("v_permlane32_swap_b32 %0, %1" : "+v"(a), "+v"(b))
#endif

__device__ __forceinline__ float EXP2(float x) {
  float r;
  asm("v_exp_f32 %0, %1" : "=v"(r) : "v"(x));
  return r;
}

// ---------------- fp32 -> bf16 convert (hidden) ----------------
__global__ __launch_bounds__(256) void cvt_bf16_kernel(const float* __restrict__ in,
                                                       bf16_t* __restrict__ out, int n) {
  int i = (blockIdx.x * 256 + threadIdx.x) * 8;
  if (i >= n) return;
  float4 a = *(const float4*)(in + i);
  float4 b = *(const float4*)(in + i + 4);
  union { int4 i4; bf16_t h[8]; } u;
  u.h[0] = (bf16_t)a.x; u.h[1] = (bf16_t)a.y; u.h[2] = (bf16_t)a.z; u.h[3] = (bf16_t)a.w;
  u.h[4] = (bf16_t)b.x; u.h[5] = (bf16_t)b.y; u.h[6] = (bf16_t)b.z; u.h[7] = (bf16_t)b.w;
  *(int4*)(out + i) = u.i4;
}

// ---------------- W [k][n] fp32 -> WT [n][k] bf16 ----------------
__global__ __launch_bounds__(256) void transposeW_kernel(const float* __restrict__ Wq,
                                                         const float* __restrict__ Wk,
                                                         const float* __restrict__ Wv,
                                                         bf16_t* __restrict__ WT) {
  __shared__ float tile[32][33];
  int z = blockIdx.z;
  const float* W = (z == 0) ? Wq : (z == 1) ? Wk : Wv;
  bf16_t* Out = WT + (size_t)z * HH * HH;
  int tx = threadIdx.x, ty = threadIdx.y;
  int x0 = blockIdx.x * 32;  // n
  int y0 = blockIdx.y * 32;  // k
  for (int j = ty; j < 32; j += 8)
    tile[j][tx] = W[(size_t)(y0 + j) * HH + x0 + tx];
  __syncthreads();
  for (int j = ty; j < 32; j += 8)
    Out[(size_t)(x0 + j) * HH + y0 + tx] = (bf16_t)tile[tx][j];
}

// ---------------- QKV GEMM: BM=128 x BN=384, BK=64, 256 blocks (1/CU), 2-buf ----------------
#define BMT 128
#define BNT 384
#define BKT 64
#define NTL 16
#define BUFBYTES 65536  // (128+384)*64*2

__global__ __launch_bounds__(512, 2) void qkv_gemm2(const bf16_t* __restrict__ hiddenB,
                                                    const bf16_t* __restrict__ WT,
                                                    const float* __restrict__ bq,
                                                    const float* __restrict__ bk,
                                                    const float* __restrict__ bv,
                                                    bf16_t* __restrict__ Qo,
                                                    bf16_t* __restrict__ Ko,
                                                    bf16_t* __restrict__ Vt) {
  __shared__ bf16_t smem[2 * BUFBYTES / 2];  // 128 KB

  // XCD swizzle: 256 wgs = 8 XCD x 32; nb fastest -> A panel + B slice stay per-XCD
  const int wg = blockIdx.x;
  const int id = (wg & 7) * 32 + (wg >> 3);
  const int nb = id & 7;    // N / 384
  const int mb = id >> 3;   // M / 128

  const int t = threadIdx.x;
  const int lane = t & 63;
  const int w = t >> 6;      // 0..7
  const int wr = w >> 2;     // 0..1 (M, 64 rows)
  const int wc = w & 3;      // 0..3 (N, 96 cols)
  const int lr = lane & 15;
  const int g4 = lane >> 4;  // 0..3

  const unsigned schunk = (((unsigned)(t & 7)) ^ ((unsigned)((t >> 3) & 7))) << 4;
  const char* Ag = (const char*)hiddenB + (size_t)(mb * BMT) * 2048;
  const char* Bg = (const char*)WT + (size_t)(nb * BNT) * 2048;

  // one issue = 64 rows x 128B = 8KB; thread t covers row (t>>3), chunk (t&7)
  auto stage = [&](const char* gb, int growbase, int kbyte, char* ldsdest) {
    gload_lds16(gb + (size_t)(growbase + (t >> 3)) * 2048 + kbyte + schunk,
                ldsdest + w * 1024);
  };
  const unsigned axor = ((unsigned)(lr & 7)) << 4;

  f32x4 acc[4][6] = {};

  // prologue: stage tile 0
  {
    char* S0 = (char*)smem;
    stage(Ag, 0, 0, S0);
    stage(Ag, 64, 0, S0 + 8192);
#pragma unroll
    for (int i = 0; i < 6; ++i) stage(Bg, i * 64, 0, S0 + 16384 + i * 8192);
  }
  asm volatile("s_waitcnt vmcnt(0)" ::: "memory");
  __builtin_amdgcn_s_barrier();

  for (int j = 0; j < NTL; ++j) {
    const char* Ab = (const char*)smem + (j & 1) * BUFBYTES;
    const char* Bb = Ab + 16384;
    char* Sb = (char*)smem + ((j + 1) & 1) * BUFBYTES;
    const int kb = (j + 1) * 128;
    const bool st = (j + 1 < NTL);

    if (st) { stage(Ag, 0, kb, Sb); stage(Ag, 64, kb, Sb + 8192); }

    bf16x8 af[4][2];
#pragma unroll
    for (int mi = 0; mi < 4; ++mi)
#pragma unroll
      for (int ks = 0; ks < 2; ++ks)
        af[mi][ks] = *(const bf16x8*)(Ab + (size_t)(wr * 64 + mi * 16 + lr) * 128 +
                                      (((unsigned)(ks * 64 + g4 * 16)) ^ axor));

#pragma unroll
    for (int p = 0; p < 3; ++p) {
      if (st) {
        stage(Bg, (2 * p) * 64, kb, Sb + 16384 + (2 * p) * 8192);
        stage(Bg, (2 * p + 1) * 64, kb, Sb + 16384 + (2 * p + 1) * 8192);
      }
      bf16x8 b0[2], b1[2];
#pragma unroll
      for (int ks = 0; ks < 2; ++ks) {
        b0[ks] = *(const bf16x8*)(Bb + (size_t)(wc * 96 + (2 * p) * 16 + lr) * 128 +
                                  (((unsigned)(ks * 64 + g4 * 16)) ^ axor));
        b1[ks] = *(const bf16x8*)(Bb + (size_t)(wc * 96 + (2 * p + 1) * 16 + lr) * 128 +
                                  (((unsigned)(ks * 64 + g4 * 16)) ^ axor));
      }
      __builtin_amdgcn_s_setprio(1);
#pragma unroll
      for (int mi = 0; mi < 4; ++mi)
#pragma unroll
        for (int ks = 0; ks < 2; ++ks) {
          acc[mi][2 * p] = MFMA16(af[mi][ks], b0[ks], acc[mi][2 * p]);
          acc[mi][2 * p + 1] = MFMA16(af[mi][ks], b1[ks], acc[mi][2 * p + 1]);
        }
      __builtin_amdgcn_s_setprio(0);
    }

    if (st) {
      asm volatile("s_waitcnt vmcnt(0)" ::: "memory");
      __builtin_amdgcn_s_barrier();
    }
  }

  // epilogue: bias + scatter; per 16-col chunk select z (chunks never straddle z)
#pragma unroll
  for (int ni = 0; ni < 6; ++ni) {
    int col = nb * BNT + wc * 96 + ni * 16 + lr;
    int z = col >> 10;
    int ci = col & 1023;
    const float* bias = (z == 0) ? bq : (z == 1) ? bk : bv;
    float bia = bias[ci];
    int hh = ci >> 6, d = ci & 63;
    if (z < 2) {
      bf16_t* Out = (z == 0) ? Qo : Ko;
#pragma unroll
      for (int mi = 0; mi < 4; ++mi) {
#pragma unroll
        for (int r = 0; r < 4; ++r) {
          int row = mb * BMT + wr * 64 + mi * 16 + g4 * 4 + r;
          int b = row >> 10, s = row & 1023;
          Out[((size_t)(b * NHEAD + hh) * SS + s) * HDIM + d] = (bf16_t)(acc[mi][ni][r] + bia);
        }
      }
    } else {
#pragma unroll
      for (int mi = 0; mi < 4; ++mi) {
        int row0 = mb * BMT + wr * 64 + mi * 16 + g4 * 4;
        int b = row0 >> 10, s0 = row0 & 1023;
        float v0 = acc[mi][ni][0] + bia, v1 = acc[mi][ni][1] + bia;
        float v2 = acc[mi][ni][2] + bia, v3 = acc[mi][ni][3] + bia;
        unsigned u0, u1;
        asm("v_cvt_pk_bf16_f32 %0, %1, %2" : "=v"(u0) : "v"(v0), "v"(v1));
        asm("v_cvt_pk_bf16_f32 %0, %1, %2" : "=v"(u1) : "v"(v2), "v"(v3));
        uint2 pv; pv.x = u0; pv.y = u1;
        *(uint2*)&Vt[((size_t)(b * NHEAD + hh) * HDIM + d) * SS + s0] = pv;
      }
    }
  }
}

// ---------------- fused flash attention v6: split-KV 8-wave, in-LDS merge ----------------
// Waves 0-3: kv [0,512) for 128 q-rows; waves 4-7: kv [512,1024) for the SAME q-rows.
// 4096 waves total = 4 waves/SIMD (2x r7). Each half has its own double-buffered
// K/V pipeline (16KB/buf); per-tile: stage(t+1) -> compute(t) -> vmcnt(0)+barrier.
// Final: upper waves publish unnormalized O^T+(m,l) to LDS; lower waves combine.
// Softmax in log2 domain (Q pre-scaled 0.125*log2e, mask *log2e), batched over 64 kv.
__global__ __launch_bounds__(512, 4) void attn6_kernel(const bf16_t* __restrict__ Q,
                                                       const bf16_t* __restrict__ K,
                                                       const bf16_t* __restrict__ Vt,
                                                       const float* __restrict__ mask,
                                                       float* __restrict__ out) {
  __shared__ bf16_t KVsm[2][2][2][64 * 64];  // [half][buf][K/V][8KB] = 64 KB
  __shared__ float Msm[SS];                  // 4 KB

  const int wg = blockIdx.x;
  const int id = (wg & 7) * 64 + (wg >> 3);
  const int xblk = id & 7;
  const int bh = id >> 3;

  const int b = bh >> 4;
  const int h = bh & 15;
  const int t = threadIdx.x;
  const int lane = t & 63;
  const int w = t >> 6;        // 0..7
  const int wl = w & 3;        // q-group
  const int half = w >> 2;     // kv half
  const int l31 = lane & 31;
  const int hi = lane >> 5;
  const int q0 = xblk * 128 + wl * 32;
  const int kvbase = half * 512;

  const bf16_t* Qh = Q + (size_t)bh * SS * HDIM;
  const bf16_t* Kh = K + (size_t)bh * SS * HDIM;
  const bf16_t* Vh = Vt + (size_t)bh * HDIM * SS;  // [d][s]

  const float L2E = 1.4426950408889634f;
  if (t < 256) {
    float4 mv = *(const float4*)&mask[(size_t)b * SS + t * 4];
    mv.x *= L2E; mv.y *= L2E; mv.z *= L2E; mv.w *= L2E;
    *(float4*)&Msm[t * 4] = mv;
  }

  // Q fragments pre-scaled by 0.125*log2e (log2-domain scores)
  bf16x8 qb[4];
#pragma unroll
  for (int c = 0; c < 4; ++c) {
    bf16x8 q = *(const bf16x8*)&Qh[(size_t)(q0 + l31) * HDIM + c * 16 + hi * 8];
#pragma unroll
    for (int e = 0; e < 8; ++e) q[e] = (bf16_t)((float)q[e] * (0.125f * L2E));
    qb[c] = q;
  }

  const int srow = lane >> 3;
  const unsigned gcol = ((lane & 7) * 16) ^ (srow << 4);
  const unsigned swz = (unsigned)((l31 & 7) << 4);

  // stage one 64-kv tile of this wave's half: 4 gloads/thread (16 K rows + 16 V rows)
  auto stageKV = [&](int tile, int buf) {
    const int kv0 = kvbase + tile * 64;
#pragma unroll
    for (int i = 0; i < 2; ++i) {
      int rbase = wl * 16 + i * 8;
      gload_lds16((const char*)Kh + (size_t)(kv0 + rbase + srow) * 128 + gcol,
                  (char*)&KVsm[half][buf][0][0] + (size_t)rbase * 128);
      gload_lds16((const char*)Vh + (size_t)(rbase + srow) * 2048 + (size_t)kv0 * 2 + gcol,
                  (char*)&KVsm[half][buf][1][0] + (size_t)rbase * 128);
    }
  };

  f32x16 acc0 = {}, acc1 = {};
  float m_run = -1e30f, l_run = 0.f;

  stageKV(0, 0);
  asm volatile("s_waitcnt vmcnt(0)" ::: "memory");
  __builtin_amdgcn_s_barrier();

  for (int tt = 0; tt < 8; ++tt) {
    if (tt + 1 < 8) stageKV(tt + 1, (tt + 1) & 1);
    const char* Kb = (const char*)&KVsm[half][tt & 1][0][0];
    const char* Vb = (const char*)&KVsm[half][tt & 1][1][0];
    const int kv0 = kvbase + tt * 64;

    // ---- QK^T for both 32-kv halves ----
    f32x16 st0 = {}, st1 = {};
    __builtin_amdgcn_s_setprio(1);
#pragma unroll
    for (int c = 0; c < 4; ++c) {
      bf16x8 kf0 = *(const bf16x8*)(Kb + (size_t)l31 * 128 + ((unsigned)(c * 32 + hi * 16) ^ swz));
      st0 = MFMA32(kf0, qb[c], st0);
    }
#pragma unroll
    for (int c = 0; c < 4; ++c) {
      bf16x8 kf1 = *(const bf16x8*)(Kb + (size_t)(32 + l31) * 128 + ((unsigned)(c * 32 + hi * 16) ^ swz));
      st1 = MFMA32(kf1, qb[c], st1);
    }
    __builtin_amdgcn_s_setprio(0);

    // ---- + mask (log2-scaled) ----
#pragma unroll
    for (int k2 = 0; k2 < 8; ++k2) {
      int off = 8 * (k2 >> 1) + 4 * hi + 2 * (k2 & 1);
      float2 m0v = *(const float2*)&Msm[kv0 + off];
      float2 m1v = *(const float2*)&Msm[kv0 + 32 + off];
      st0[2 * k2] += m0v.x; st0[2 * k2 + 1] += m0v.y;
      st1[2 * k2] += m1v.x; st1[2 * k2 + 1] += m1v.y;
    }

    // ---- max via pairwise + max3 tree ----
    float v0 = fmaxf(st0[0], st1[0]),  v1 = fmaxf(st0[1], st1[1]);
    float v2 = fmaxf(st0[2], st1[2]),  v3 = fmaxf(st0[3], st1[3]);
    float v4 = fmaxf(st0[4], st1[4]),  v5 = fmaxf(st0[5], st1[5]);
    float v6 = fmaxf(st0[6], st1[6]),  v7 = fmaxf(st0[7], st1[7]);
    float v8 = fmaxf(st0[8], st1[8]),  v9 = fmaxf(st0[9], st1[9]);
    float v10 = fmaxf(st0[10], st1[10]), v11 = fmaxf(st0[11], st1[11]);
    float v12 = fmaxf(st0[12], st1[12]), v13 = fmaxf(st0[13], st1[13]);
    float v14 = fmaxf(st0[14], st1[14]), v15 = fmaxf(st0[15], st1[15]);
    float g0 = fmaxf(fmaxf(v0, v1), v2);
    float g1 = fmaxf(fmaxf(v3, v4), v5);
    float g2 = fmaxf(fmaxf(v6, v7), v8);
    float g3 = fmaxf(fmaxf(v9, v10), v11);
    float g4 = fmaxf(fmaxf(v12, v13), v14);
    float mj = fmaxf(fmaxf(fmaxf(g0, g1), g2), fmaxf(fmaxf(g3, g4), v15));
    mj = fmaxf(mj, __shfl_xor(mj, 32));

    // ---- defer-max (THR = 8 bits) ----
    if (!__all(mj <= m_run + 8.f)) {
      float mnew = fmaxf(m_run, mj);
      float corr = EXP2(m_run - mnew);
#pragma unroll
      for (int r = 0; r < 16; ++r) { acc0[r] *= corr; acc1[r] *= corr; }
      l_run *= corr;
      m_run = mnew;
    }

    // ---- p = 2^(st - m) ----
#pragma unroll
    for (int r = 0; r < 16; ++r) st0[r] = EXP2(st0[r] - m_run);
#pragma unroll
    for (int r = 0; r < 16; ++r) st1[r] = EXP2(st1[r] - m_run);

    // ---- sum: balanced tree over 32 ----
    float s0 = (st0[0] + st1[0]) + (st0[1] + st1[1]);
    float s1 = (st0[2] + st1[2]) + (st0[3] + st1[3]);
    float s2 = (st0[4] + st1[4]) + (st0[5] + st1[5]);
    float s3 = (st0[6] + st1[6]) + (st0[7] + st1[7]);
    float s4 = (st0[8] + st1[8]) + (st0[9] + st1[9]);
    float s5 = (st0[10] + st1[10]) + (st0[11] + st1[11]);
    float s6 = (st0[12] + st1[12]) + (st0[13] + st1[13]);
    float s7 = (st0[14] + st1[14]) + (st0[15] + st1[15]);
    float ls = ((s0 + s1) + (s2 + s3)) + ((s4 + s5) + (s6 + s7));
    ls += __shfl_xor(ls, 32);
    l_run += ls;

    // ---- pack both P halves into B-frags ----
    unsigned wd0[8], wd1[8];
#pragma unroll
    for (int k2 = 0; k2 < 8; ++k2) {
      unsigned r0, r1;
      float a0f = st0[2 * k2], a1f = st0[2 * k2 + 1];
      float b0f = st1[2 * k2], b1f = st1[2 * k2 + 1];
      asm("v_cvt_pk_bf16_f32 %0, %1, %2" : "=v"(r0) : "v"(a0f), "v"(a1f));
      asm("v_cvt_pk_bf16_f32 %0, %1, %2" : "=v"(r1) : "v"(b0f), "v"(b1f));
      wd0[k2] = r0; wd1[k2] = r1;
    }
    unsigned a0 = wd0[0], b0 = wd0[2]; PSWAP(a0, b0);
    unsigned a1 = wd0[1], b1 = wd0[3]; PSWAP(a1, b1);
    unsigned a2 = wd0[4], b2 = wd0[6]; PSWAP(a2, b2);
    unsigned a3 = wd0[5], b3 = wd0[7]; PSWAP(a3, b3);
    unsigned c0 = wd1[0], d0 = wd1[2]; PSWAP(c0, d0);
    unsigned c1 = wd1[1], d1 = wd1[3]; PSWAP(c1, d1);
    unsigned c2 = wd1[4], d2 = wd1[6]; PSWAP(c2, d2);
    unsigned c3 = wd1[5], d3 = wd1[7]; PSWAP(c3, d3);
    union { unsigned u[4]; bf16x8 v; } pf0, pf1, pf2, pf3;
    pf0.u[0] = a0; pf0.u[1] = a1; pf0.u[2] = b0; pf0.u[3] = b1;
    pf1.u[0] = a2; pf1.u[1] = a3; pf1.u[2] = b2; pf1.u[3] = b3;
    pf2.u[0] = c0; pf2.u[1] = c1; pf2.u[2] = d0; pf2.u[3] = d1;
    pf3.u[0] = c2; pf3.u[1] = c3; pf3.u[2] = d2; pf3.u[3] = d3;

    // ---- O^T += V^T . P^T ----
    __builtin_amdgcn_s_setprio(1);
    {
      bf16x8 vf;
      vf = *(const bf16x8*)(Vb + (size_t)(l31) * 128 + ((unsigned)(0 * 32 + hi * 16) ^ swz));
      acc0 = MFMA32(vf, pf0.v, acc0);
      vf = *(const bf16x8*)(Vb + (size_t)(32 + l31) * 128 + ((unsigned)(0 * 32 + hi * 16) ^ swz));
      acc1 = MFMA32(vf, pf0.v, acc1);
      vf = *(const bf16x8*)(Vb + (size_t)(l31) * 128 + ((unsigned)(1 * 32 + hi * 16) ^ swz));
      acc0 = MFMA32(vf, pf1.v, acc0);
      vf = *(const bf16x8*)(Vb + (size_t)(32 + l31) * 128 + ((unsigned)(1 * 32 + hi * 16) ^ swz));
      acc1 = MFMA32(vf, pf1.v, acc1);
      vf = *(const bf16x8*)(Vb + (size_t)(l31) * 128 + ((unsigned)(2 * 32 + hi * 16) ^ swz));
      acc0 = MFMA32(vf, pf2.v, acc0);
      vf = *(const bf16x8*)(Vb + (size_t)(32 + l31) * 128 + ((unsigned)(2 * 32 + hi * 16) ^ swz));
      acc1 = MFMA32(vf, pf2.v, acc1);
      vf = *(const bf16x8*)(Vb + (size_t)(l31) * 128 + ((unsigned)(3 * 32 + hi * 16) ^ swz));
      acc0 = MFMA32(vf, pf3.v, acc0);
      vf = *(const bf16x8*)(Vb + (size_t)(32 + l31) * 128 + ((unsigned)(3 * 32 + hi * 16) ^ swz));
      acc1 = MFMA32(vf, pf3.v, acc1);
    }
    __builtin_amdgcn_s_setprio(0);

    asm volatile("s_waitcnt vmcnt(0)" ::: "memory");
    __builtin_amdgcn_s_barrier();
  }

  // ---- split-KV merge via LDS (stride-36 float4) ----
  __syncthreads();
  float* mb = (float*)&KVsm[0][0][0][0];
  if (half == 1) {
    float* dst = mb + ((size_t)(wl * 64 + lane)) * 36;
#pragma unroll
    for (int g = 0; g < 4; ++g) {
      float4 w0, w1;
      w0.x = acc0[g * 4 + 0]; w0.y = acc0[g * 4 + 1];
      w0.z = acc0[g * 4 + 2]; w0.w = acc0[g * 4 + 3];
      w1.x = acc1[g * 4 + 0]; w1.y = acc1[g * 4 + 1];
      w1.z = acc1[g * 4 + 2]; w1.w = acc1[g * 4 + 3];
      *(float4*)(dst + g * 4) = w0;
      *(float4*)(dst + 16 + g * 4) = w1;
    }
    dst[32] = m_run; dst[33] = l_run;
  }
  __syncthreads();
  if (half == 0) {
    const float* src = mb + ((size_t)(wl * 64 + lane)) * 36;
    float m1 = src[32], l1 = src[33];
    float m = fmaxf(m_run, m1);
    float f0 = EXP2(m_run - m), f1 = EXP2(m1 - m);
    float rinv = 1.0f / (l_run * f0 + l1 * f1);
    float fr0 = f0 * rinv, fr1 = f1 * rinv;
    int q = q0 + l31;
    float* ob = out + ((size_t)(b * SS + q)) * HH + h * HDIM;
#pragma unroll
    for (int g = 0; g < 4; ++g) {
      float4 o0, o1;
      o0.x = acc0[g * 4 + 0] * fr0 + src[g * 4 + 0] * fr1;
      o0.y = acc0[g * 4 + 1] * fr0 + src[g * 4 + 1] * fr1;
      o0.z = acc0[g * 4 + 2] * fr0 + src[g * 4 + 2] * fr1;
      o0.w = acc0[g * 4 + 3] * fr0 + src[g * 4 + 3] * fr1;
      o1.x = acc1[g * 4 + 0] * fr0 + src[16 + g * 4 + 0] * fr1;
      o1.y = acc1[g * 4 + 1] * fr0 + src[16 + g * 4 + 1] * fr1;
      o1.z = acc1[g * 4 + 2] * fr0 + src[16 + g * 4 + 2] * fr1;
      o1.w = acc1[g * 4 + 3] * fr0 + src[16 + g * 4 + 3] * fr1;
      *(float4*)&ob[g * 8 + 4 * hi] = o0;
      *(float4*)&ob[32 + g * 8 + 4 * hi] = o1;
    }
  }
}

// ---------------- launch ----------------
extern "C" void kernel_launch(void* const* d_in, const int* in_sizes, int n_in,
                              void* d_out, int out_size, void* d_ws, size_t ws_size,
                              hipStream_t stream) {
  const float* hs   = (const float*)d_in[0];
  const float* mask = (const float*)d_in[1];
  const float* Wq   = (const float*)d_in[2];
  const float* bq   = (const float*)d_in[3];
  const float* Wk   = (const float*)d_in[4];
  const float* bk   = (const float*)d_in[5];
  const float* Wv   = (const float*)d_in[6];
  const float* bv   = (const float*)d_in[7];
  float* out = (float*)d_out;

  char* ws = (char*)d_ws;
  bf16_t* hiddenB = (bf16_t*)ws;                                  // 8 MB
  bf16_t* WT      = (bf16_t*)(ws + (size_t)8 * 1024 * 1024);      // 6 MB
  bf16_t* Qb      = (bf16_t*)(ws + (size_t)14 * 1024 * 1024);     // 8 MB
  bf16_t* Kb      = (bf16_t*)(ws + (size_t)22 * 1024 * 1024);     // 8 MB
  bf16_t* Vt      = (bf16_t*)(ws + (size_t)30 * 1024 * 1024);     // 8 MB

  cvt_bf16_kernel<<<MM * HH / (256 * 8), 256, 0, stream>>>(hs, hiddenB, MM * HH);
  transposeW_kernel<<<dim3(32, 32, 3), dim3(32, 8), 0, stream>>>(Wq, Wk, Wv, WT);
  qkv_gemm2<<<256, 512, 0, stream>>>(hiddenB, WT, bq, bk, bv, Qb, Kb, Vt);
  attn6_kernel<<<512, 512, 0, stream>>>(Qb, Kb, Vt, mask, out);
}